// Round 3
// baseline (262.853 us; speedup 1.0000x reference)
//
#include <hip/hip_runtime.h>

// MaxPool2d: X (16, 64, 512, 512) f32, kernel=2, stride=2, VALID
// -> out (16, 64, 256, 256) f32.
// Memory-bound streaming op (1.074 GB read + 268 MB write, each byte once).
// R2 = R1 theory with compile fix: nontemporal builtins need Clang
// ext_vector_type, not HIP_vector_type structs.
//  - grid-stride loop with 2048 blocks (G11)
//  - nontemporal loads/stores (data touched exactly once)

typedef float f32x4 __attribute__((ext_vector_type(4)));
typedef float f32x2 __attribute__((ext_vector_type(2)));

__global__ __launch_bounds__(256) void SvegaMaxPool2x2_kernel(
    const f32x4* __restrict__ X4,   // input viewed as float-vec4
    f32x2* __restrict__ Y2,         // output viewed as float-vec2
    int nthreads)                   // total output-pairs
{
    int stride = gridDim.x * blockDim.x;
    for (int t = blockIdx.x * blockDim.x + threadIdx.x; t < nthreads; t += stride) {
        // Each plane: input 512x512 (= 65536 vec4), output 256x256 (= 32768 pairs)
        int plane = t >> 15;          // / 32768 pairs per plane
        int p     = t & 32767;
        int oh    = p >> 7;           // output row (128 pairs per output row)
        int pw    = p & 127;          // pair index within row

        // input vec4 index: plane*65536 + (oh*2)*128 + pw
        long base = ((long)plane << 16) + (oh << 8) + pw;

        f32x4 r0 = __builtin_nontemporal_load(&X4[base]);        // row 2*oh
        f32x4 r1 = __builtin_nontemporal_load(&X4[base + 128]);  // row 2*oh+1

        f32x2 out;
        out.x = fmaxf(fmaxf(r0.x, r0.y), fmaxf(r1.x, r1.y));
        out.y = fmaxf(fmaxf(r0.z, r0.w), fmaxf(r1.z, r1.w));

        __builtin_nontemporal_store(out, &Y2[t]);
    }
}

extern "C" void kernel_launch(void* const* d_in, const int* in_sizes, int n_in,
                              void* d_out, int out_size, void* d_ws, size_t ws_size,
                              hipStream_t stream) {
    const f32x4* X4 = (const f32x4*)d_in[0];
    f32x2* Y2 = (f32x2*)d_out;

    int nthreads = out_size / 2;     // 33,554,432 output-pairs
    int blocks = 2048;               // 8 blocks/CU, grid-stride covers the rest

    SvegaMaxPool2x2_kernel<<<blocks, 256, 0, stream>>>(X4, Y2, nthreads);
}

// Round 4
// 246.425 us; speedup vs baseline: 1.0667x; 1.0667x over previous
//
#include <hip/hip_runtime.h>

// MaxPool2d: X (16, 64, 512, 512) f32, kernel=2, stride=2, VALID
// -> out (16, 64, 256, 256) f32.
// Memory-bound streaming op (1.074 GB read + 268 MB write, each byte once).
//
// R3 = R0 structure (238us, 5.63 TB/s; R2's grid-stride+NT regressed to 263)
// + exactly one change: 2-way per-thread ILP. Each thread handles pair t and
// pair t+half (half = 512 full planes away), issuing 4 independent coalesced
// float4 loads before any dependent max/store. Tests whether R0 was
// MLP-limited or already at the mixed-stream roofline.

__global__ __launch_bounds__(256) void SvegaMaxPool2x2_kernel(
    const float4* __restrict__ X4,   // input viewed as float4
    float2* __restrict__ Y2,         // output viewed as float2
    int half)                        // nthreads/2 = 16,777,216
{
    int t = blockIdx.x * blockDim.x + threadIdx.x;
    if (t >= half) return;

    // Pair A = t; Pair B = t + half (exactly 512 planes later in input).
    // Each plane: input 512x512 (= 65536 float4), output 256x256 (= 32768 pairs)
    int plane = t >> 15;
    int p     = t & 32767;
    int oh    = p >> 7;
    int pw    = p & 127;

    long baseA = ((long)plane << 16) + (oh << 8) + pw;
    long baseB = baseA + (512L << 16);   // +512 planes

    // 4 independent coalesced loads in flight
    float4 a0 = X4[baseA];
    float4 a1 = X4[baseA + 128];
    float4 b0 = X4[baseB];
    float4 b1 = X4[baseB + 128];

    float2 oA, oB;
    oA.x = fmaxf(fmaxf(a0.x, a0.y), fmaxf(a1.x, a1.y));
    oA.y = fmaxf(fmaxf(a0.z, a0.w), fmaxf(a1.z, a1.w));
    oB.x = fmaxf(fmaxf(b0.x, b0.y), fmaxf(b1.x, b1.y));
    oB.y = fmaxf(fmaxf(b0.z, b0.w), fmaxf(b1.z, b1.w));

    Y2[t]        = oA;
    Y2[t + half] = oB;
}

extern "C" void kernel_launch(void* const* d_in, const int* in_sizes, int n_in,
                              void* d_out, int out_size, void* d_ws, size_t ws_size,
                              hipStream_t stream) {
    const float4* X4 = (const float4*)d_in[0];
    float2* Y2 = (float2*)d_out;

    int half = out_size / 4;                 // 16,777,216 threads
    int blocks = (half + 255) / 256;         // 65,536

    SvegaMaxPool2x2_kernel<<<blocks, 256, 0, stream>>>(X4, Y2, half);
}

// Round 5
// 241.543 us; speedup vs baseline: 1.0882x; 1.0202x over previous
//
#include <hip/hip_runtime.h>

// MaxPool2d: X (16, 64, 512, 512) f32, kernel=2, stride=2, VALID
// -> out (16, 64, 256, 256) f32.
// Memory-bound streaming op (1.074 GB read + 268 MB write, each byte once).
//
// History: R0 pair/thread = 238.4us (5.63 TB/s). R2 grid-stride+NT = 262.9us.
// R3 ILP x2 (far pair) = 246.4us. Both reverted.
// R4 = R0 + wide stores: one thread owns 4 consecutive output pixels ->
// single float4 store (16B/lane, matching the 6.3+ TB/s reference kernels'
// store width). Loads become 2 paired dwordx4 at 32B/lane stride; the pair
// covers each 64B line fully (complement hits L1), so HBM read traffic
// is unchanged.

__global__ __launch_bounds__(256) void SvegaMaxPool2x2_kernel(
    const float4* __restrict__ X4,   // input viewed as float4
    float4* __restrict__ Y4,         // output viewed as float4
    int nquads)                      // total output quads = out_size/4
{
    int t = blockIdx.x * blockDim.x + threadIdx.x;
    if (t >= nquads) return;

    // Per plane: output 256x256 px = 16384 quads (64 quads/row);
    //            input 512x512 = 65536 float4 (128/row).
    int plane = t >> 14;
    int p     = t & 16383;
    int oh    = p >> 6;           // output row
    int qw    = p & 63;           // quad index within row

    // input float4 base: plane*65536 + (2*oh)*128 + 2*qw
    long base = ((long)plane << 16) + (oh << 8) + (qw << 1);

    float4 r0a = X4[base];         // row 2*oh,   cols 8qw+0..3
    float4 r0b = X4[base + 1];     // row 2*oh,   cols 8qw+4..7
    float4 r1a = X4[base + 128];   // row 2*oh+1, cols 8qw+0..3
    float4 r1b = X4[base + 129];   // row 2*oh+1, cols 8qw+4..7

    float4 out;
    out.x = fmaxf(fmaxf(r0a.x, r0a.y), fmaxf(r1a.x, r1a.y));
    out.y = fmaxf(fmaxf(r0a.z, r0a.w), fmaxf(r1a.z, r1a.w));
    out.z = fmaxf(fmaxf(r0b.x, r0b.y), fmaxf(r1b.x, r1b.y));
    out.w = fmaxf(fmaxf(r0b.z, r0b.w), fmaxf(r1b.z, r1b.w));

    Y4[t] = out;
}

extern "C" void kernel_launch(void* const* d_in, const int* in_sizes, int n_in,
                              void* d_out, int out_size, void* d_ws, size_t ws_size,
                              hipStream_t stream) {
    const float4* X4 = (const float4*)d_in[0];
    float4* Y4 = (float4*)d_out;

    int nquads = out_size / 4;               // 16,777,216
    int blocks = (nquads + 255) / 256;       // 65,536

    SvegaMaxPool2x2_kernel<<<blocks, 256, 0, stream>>>(X4, Y4, nquads);
}